// Round 11
// baseline (179.843 us; speedup 1.0000x reference)
//
#include <hip/hip_runtime.h>
#include <stdint.h>

#define Bb 2
#define Ss 2048
#define Dd 1024
#define Hh 8
#define Ee 128
#define KWW 16
#define Mm (Bb*Ss)   // 4096
#define Kk 1024      // K for both GEMMs
#define PANEL 131072 // 128 rows x 1024 k, frag-major [kc 128][r 128][8]

typedef unsigned short u16;
typedef __attribute__((ext_vector_type(8))) _Float16 f16x8;  // 8 fp16 (4 VGPRs)
typedef __attribute__((ext_vector_type(4))) float f32x4;

// fp32 -> fp16 (RTN)
__device__ __forceinline__ u16 f2h(float f) {
  union { _Float16 h; u16 u; } v; v.h = (_Float16)f; return v.u;
}
__device__ __forceinline__ float h2f(u16 u) {
  union { u16 u; _Float16 h; } v; v.u = u; return (float)v.h;
}
__device__ __forceinline__ float h2f_lo(uint32_t w) { return h2f((u16)(w & 0xFFFF)); }
__device__ __forceinline__ float h2f_hi(uint32_t w) { return h2f((u16)(w >> 16)); }

// ---------------- fused prep kernel ----------------
// EVERYTHING fragment-major [kc][r][8] (kc = k/8) so both GEMM operands are
// per-lane b128 global loads (no LDS, no barriers in the GEMM K-loop).
// blocks [0,4096): x [m][d] f32 -> xhf[mb][kc][mm][8] f16  (bid = mb*128+kc)
// blocks [4096,7168): Wq/Wk/Wv [h][D][E] -> wT[z][kc][n(E)][8], z=proj*8+h
// blocks [7168,8192): Wo [h*E][D] -> woT[nb][kc][nn][8], n = nb*128+nn over D
__global__ __launch_bounds__(256) void prep(
    const float* __restrict__ x, const float* __restrict__ Wq,
    const float* __restrict__ Wk, const float* __restrict__ Wv,
    const float* __restrict__ Wo,
    u16* __restrict__ xhf, u16* __restrict__ wT, u16* __restrict__ woT) {
  const int bid = blockIdx.x;
  const int tid = threadIdx.x;
  if (bid < 4096) {
    const int mb = bid >> 7, kc = bid & 127;
    const int mm = tid >> 1, k7 = (tid & 1) * 4;
    float4 f = *(const float4*)(x + ((size_t)(mb * 128 + mm) << 10) + kc * 8 + k7);
    uint64_t pk = (uint64_t)f2h(f.x) | ((uint64_t)f2h(f.y) << 16) |
                  ((uint64_t)f2h(f.z) << 32) | ((uint64_t)f2h(f.w) << 48);
    *(uint64_t*)(xhf + (size_t)bid * 1024 + mm * 8 + k7) = pk;
    return;
  }
  __shared__ float tile[32][33];  // +1 pad: bank-conflict-free
  const int tx = tid & 31, ty = tid >> 5;  // (32,8) shape
  if (bid < 4096 + 3072) {
    const int idx = bid - 4096;
    const int z = idx >> 7, rem = idx & 127;
    const int h = z & 7;
    const float* W = (z < 8) ? Wq : (z < 16) ? Wk : Wv;
    const float* ib = W + (size_t)h * Dd * Ee;
    u16* ob = wT + (size_t)z * PANEL;
    const int r0 = (rem & 31) * 32, c0 = (rem >> 5) * 32;  // r over D(=k), c over E(=n)
    #pragma unroll
    for (int kq = 0; kq < 4; kq++)
      tile[ty + 8*kq][tx] = ib[(size_t)(r0 + ty + 8*kq) * Ee + (c0 + tx)];
    __syncthreads();
    const int k = r0 + tx;
    #pragma unroll
    for (int kq = 0; kq < 4; kq++) {
      const int n = c0 + ty + 8*kq;
      ob[(((size_t)(k >> 3) * 128 + n) << 3) + (k & 7)] = f2h(tile[tx][ty + 8*kq]);
    }
  } else {
    const int idx = bid - (4096 + 3072);
    const int r0 = (idx & 31) * 32, c0 = (idx >> 5) * 32;  // r over h*E(=k), c over D(=n)
    const int C = Dd;
    #pragma unroll
    for (int kq = 0; kq < 4; kq++)
      tile[ty + 8*kq][tx] = Wo[(size_t)(r0 + ty + 8*kq) * C + (c0 + tx)];
    __syncthreads();
    const int k = r0 + tx;
    #pragma unroll
    for (int kq = 0; kq < 4; kq++) {
      const int n = c0 + ty + 8*kq;
      woT[(size_t)(n >> 7) * PANEL +
          (((size_t)(k >> 3) * 128 + (n & 127)) << 3) + (k & 7)] = f2h(tile[tx][ty + 8*kq]);
    }
  }
}

// ---------------- GEMM core: direct-register, NO LDS, NO barriers (R9) ----------------
// Both operands fragment-major panels [kc 128][r 128][8]; per-lane b128 global
// loads (16 lanes x 16 B = 256 B contiguous per quad), register-double-buffered
// one 32-K window ahead; compiler emits fine-grained per-use s_waitcnt vmcnt(N).
// R11: performance depends on frag loads hitting the XCD's L2 — callers must
// map blockIdx so concurrently-resident blocks per XCD share <=4MB of panels
// (R7 counters: all pipes <20% busy = latency-bound on cross-XCD/HBM misses).
template<int MI>   // A frags per wave: 4 (MT=128) or 2 (MT=64)
__device__ __forceinline__ void gemm_direct(
    const u16* __restrict__ Af, const u16* __restrict__ Bf,
    const int aoff, f32x4 (&acc)[MI][4]) {
  const int tid = threadIdx.x;
  const int wave = tid >> 6;
  const int lane = tid & 63;
  const int fr = lane & 15;            // A: m-in-16 / B: n-in-16
  const int q  = lane >> 4;            // k quad: holds k = kt + q*8 .. +7
  const int wm = (wave >> 1) * (MI * 16) + aoff;
  const int wn = (wave & 1) * 64;
  const u16* ap = Af + ((size_t)q * 128 + wm + fr) * 8;
  const u16* bp = Bf + ((size_t)q * 128 + wn + fr) * 8;

  f16x8 a0[MI], b0[4], a1[MI], b1[4];
  auto loadw = [&](int w, f16x8 (&a)[MI], f16x8 (&b)[4]) {
    const size_t o = (size_t)w * 4096;   // kt = w*32 -> 4*128*8 elems
    #pragma unroll
    for (int i = 0; i < MI; i++) a[i] = *(const f16x8*)(ap + o + (size_t)i * 128);
    #pragma unroll
    for (int j = 0; j < 4; j++)  b[j] = *(const f16x8*)(bp + o + (size_t)j * 128);
  };
  auto comp = [&](f16x8 (&a)[MI], f16x8 (&b)[4]) {
    #pragma unroll
    for (int i = 0; i < MI; i++)
      #pragma unroll
      for (int j = 0; j < 4; j++)
        acc[i][j] = __builtin_amdgcn_mfma_f32_16x16x32_f16(a[i], b[j], acc[i][j], 0, 0, 0);
  };

  #pragma unroll
  for (int i = 0; i < MI; i++)
    #pragma unroll
    for (int j = 0; j < 4; j++)
      #pragma unroll
      for (int r = 0; r < 4; r++) acc[i][j][r] = 0.0f;

  loadw(0, a0, b0);
  for (int w = 0; w < Kk / 32; w += 2) {
    loadw((w + 1) & 31, a1, b1);   // wrap on last: wasted-but-safe loads
    comp(a0, b0);
    loadw((w + 2) & 31, a0, b0);
    comp(a1, b1);
  }
}

// C/D layout (measured m89/m91): col = lane&15, row = (lane>>4)*4 + reg

// 768 blocks, 1D. XCD-locality remap (XCD = blockIdx%8, measured heuristic):
// XCD i <- mb-group (i>>1: 8 panels, 2MB) x z-group (i&1: 12 panels, 3MB)
// -> 5MB resident working set per XCD vs 14MB with naive round-robin.
__global__ __launch_bounds__(256, 3) void gemm_qkv(
    const u16* __restrict__ xhf, const u16* __restrict__ wT,
    const float* __restrict__ bq, const float* __restrict__ bk, const float* __restrict__ bv,
    u16* __restrict__ q, u16* __restrict__ k, u16* __restrict__ v) {
  const int bid = blockIdx.x;
  const int xcd = bid & 7, slot = bid >> 3;      // slot in [0,96)
  const int mb = (xcd >> 1) * 8 + (slot & 7);    // [0,32)
  const int z  = (xcd & 1) * 12 + (slot >> 3);   // [0,24) = proj*8 + h
  const int m0 = mb * 128;
  const int proj = z >> 3, h = z & 7;
  f32x4 acc[4][4];
  gemm_direct<4>(xhf + (size_t)mb * PANEL, wT + (size_t)z * PANEL, 0, acc);

  u16* dst = proj == 0 ? q : (proj == 1 ? k : v);
  const float* bias = proj == 0 ? bq : (proj == 1 ? bk : bv);
  const int wave = threadIdx.x >> 6, lane = threadIdx.x & 63;
  const int wm = (wave >> 1) * 64, wn = (wave & 1) * 64;
  const int cn = lane & 15, rq4 = (lane >> 4) * 4;
  #pragma unroll
  for (int j = 0; j < 4; j++) {
    const int e = wn + j * 16 + cn;
    const float bb = bias[h * Ee + e];
    #pragma unroll
    for (int i = 0; i < 4; i++) {
      #pragma unroll
      for (int r = 0; r < 4; r++) {
        const int m = m0 + wm + i * 16 + rq4 + r;     // m = b*S + s
        const int b = m >> 11, s = m & (Ss - 1);
        dst[(((size_t)(b * Hh + h)) * Ss + s) * Ee + e] = f2h(acc[i][j][r] + bb);
      }
    }
  }
}

// 512 blocks, 1D. XCD i <- mb64 range [i*8, i*8+8) (1MB A) x all 8 nb (2MB B).
__global__ __launch_bounds__(256, 3) void gemm_out(
    const u16* __restrict__ attnF, const u16* __restrict__ woT,
    const float* __restrict__ bo, float* __restrict__ out) {
  const int bid = blockIdx.x;
  const int xcd = bid & 7, slot = bid >> 3;      // slot in [0,64)
  const int mb64 = xcd * 8 + (slot & 7);         // [0,64)
  const int nb = slot >> 3;                      // [0,8)
  const int m0 = mb64 * 64;
  const int n0 = nb * 128;
  f32x4 acc[2][4];
  gemm_direct<2>(attnF + (size_t)(m0 >> 7) * PANEL, woT + (size_t)nb * PANEL,
                 m0 & 64, acc);
  const int wave = threadIdx.x >> 6, lane = threadIdx.x & 63;
  const int wm = (wave >> 1) * 32, wn = (wave & 1) * 64;
  const int cn = lane & 15, rq4 = (lane >> 4) * 4;
  #pragma unroll
  for (int j = 0; j < 4; j++) {
    const int n = n0 + wn + j * 16 + cn;
    const float bb = bo[n];
    #pragma unroll
    for (int i = 0; i < 2; i++) {
      #pragma unroll
      for (int r = 0; r < 4; r++) {
        const int m = m0 + wm + i * 16 + rq4 + r;
        out[(size_t)m * Dd + n] = acc[i][j][r] + bb;
      }
    }
  }
}

// ---------------- attention: one wave per (b,h,s), fp16 loads, fp32 math ----------------
// Cross-lane plan: reduce-scatter (17 sh) -> per-lane logit j=(lane>>2) -> max/sum
// butterflies (8 sh) -> 1 exp -> allgather weights (15 sh). v rows loaded in J^t
// order so every register index is compile-time. Output written FRAGMENT-MAJOR
// ([mb][kc][mm][8], kc = (h*128+e)/8) as gemm_out's direct-register A operand.
__global__ __launch_bounds__(256) void attn_kernel(
    const u16* __restrict__ q, const u16* __restrict__ k, const u16* __restrict__ v,
    const float* __restrict__ bk, const float* __restrict__ bv,
    const int* __restrict__ dil, u16* __restrict__ attnF) {
  // XCD-contiguous swizzle: XCD i (= blockIdx%8 round-robin) gets a contiguous
  // wid range = 2 whole (b,h) panels -> disjoint ~2.5MB L2 working set per XCD.
  const int nblk = (Bb * Hh * Ss) / 4;           // 8192
  const int blk = (blockIdx.x & 7) * (nblk / 8) + (blockIdx.x >> 3);
  const int wid = blk * 4 + (threadIdx.x >> 6);
  const int lane = threadIdx.x & 63;
  const int s = wid & (Ss - 1);
  const int bh = wid >> 11;          // b*H + h
  const int h = bh & 7, b = bh >> 3;
  const int d = dil[h];
  const size_t base = (size_t)bh * Ss * Ee;      // u16 elements
  const u16* kp = k + base;
  const u16* vp = v + base;
  const uint32_t qw = *(const uint32_t*)(q + base + (size_t)s * Ee + 2 * lane);
  const float qx = h2f_lo(qw), qy = h2f_hi(qw);
  const float2 bk2 = ((const float2*)(bk + h * Ee))[lane];
  const float2 bv2 = ((const float2*)(bv + h * Ee))[lane];
  const int off = (d * (KWW - 1)) >> 1;
  const int J = (lane >> 2) & 15;

  // ---- logit partials (absolute j; in-window test is wave-uniform) ----
  float logit[KWW];
  #pragma unroll
  for (int j = 0; j < KWW; j++) {
    const int pos = s + d * j - off;
    if (pos >= 0 && pos < Ss) {
      uint32_t kw = *(const uint32_t*)(kp + (size_t)pos * Ee + 2 * lane);
      logit[j] = qx * h2f_lo(kw) + qy * h2f_hi(kw);
    } else {
      logit[j] = qx * bk2.x + qy * bk2.y;  // padded key = bias (NOT masked)
    }
  }
  // ---- v rows in J^t order (per-lane J; clamp+select, no divergent loads) ----
  float vvx[KWW], vvy[KWW];
  #pragma unroll
  for (int t = 0; t < KWW; t++) {
    const int j = J ^ t;
    const int pos = s + d * j - off;
    const int posc = min(max(pos, 0), Ss - 1);
    uint32_t vw = *(const uint32_t*)(vp + (size_t)posc * Ee + 2 * lane);
    const bool ok = (pos >= 0) && (pos < Ss);
    vvx[t] = ok ? h2f_lo(vw) : bv2.x;
    vvy[t] = ok ? h2f_hi(vw) : bv2.y;
  }

  // ---- reduce-scatter: 16 vals over 64 lanes -> lane owns j = (lane>>2) ----
  {
    const bool hi = (lane & 32) != 0;
    #pragma unroll
    for (int j = 0; j < 8; j++) {
      float send = hi ? logit[j] : logit[j + 8];
      float recv = __shfl_xor(send, 32, 64);
      logit[j] = (hi ? logit[j + 8] : logit[j]) + recv;
    }
  }
  {
    const bool hi = (lane & 16) != 0;
    #pragma unroll
    for (int j = 0; j < 4; j++) {
      float send = hi ? logit[j] : logit[j + 4];
      float recv = __shfl_xor(send, 16, 64);
      logit[j] = (hi ? logit[j + 4] : logit[j]) + recv;
    }
  }
  {
    const bool hi = (lane & 8) != 0;
    #pragma unroll
    for (int j = 0; j < 2; j++) {
      float send = hi ? logit[j] : logit[j + 2];
      float recv = __shfl_xor(send, 8, 64);
      logit[j] = (hi ? logit[j + 2] : logit[j]) + recv;
    }
  }
  float own;
  {
    const bool hi = (lane & 4) != 0;
    float send = hi ? logit[0] : logit[1];
    float recv = __shfl_xor(send, 4, 64);
    own = (hi ? logit[1] : logit[0]) + recv;
  }
  own += __shfl_xor(own, 2, 64);
  own += __shfl_xor(own, 1, 64);   // own = full logit for j = J, replicated x4

  // ---- softmax over j (j lives on lane groups; bits 0,1 already uniform) ----
  float mx = own;
  mx = fmaxf(mx, __shfl_xor(mx, 4, 64));
  mx = fmaxf(mx, __shfl_xor(mx, 8, 64));
  mx = fmaxf(mx, __shfl_xor(mx, 16, 64));
  mx = fmaxf(mx, __shfl_xor(mx, 32, 64));
  float w = __expf(own - mx);
  float sum = w;
  sum += __shfl_xor(sum, 4, 64);
  sum += __shfl_xor(sum, 8, 64);
  sum += __shfl_xor(sum, 16, 64);
  sum += __shfl_xor(sum, 32, 64);
  w *= 1.0f / (sum * 11.313708498984760f);  // /Z /sqrt(E), post-softmax quirk

  // ---- allgather: g[t] = w[J^t] ----
  float g[KWW];
  g[0] = w;
  g[1] = __shfl_xor(g[0], 4, 64);
  #pragma unroll
  for (int t = 0; t < 2; t++) g[2 + t] = __shfl_xor(g[t], 8, 64);
  #pragma unroll
  for (int t = 0; t < 4; t++) g[4 + t] = __shfl_xor(g[t], 16, 64);
  #pragma unroll
  for (int t = 0; t < 8; t++) g[8 + t] = __shfl_xor(g[t], 32, 64);

  float ax = 0.f, ay = 0.f;
  #pragma unroll
  for (int t = 0; t < KWW; t++) { ax += g[t] * vvx[t]; ay += g[t] * vvy[t]; }

  // fragment-major write: m = b*S+s, k = h*128 + e (e = 2*lane, 2*lane+1)
  const int m = b * Ss + s;
  const int mb = m >> 7, mm = m & 127;
  const int e0 = 2 * lane;
  const int kc = h * 16 + (e0 >> 3);
  u16* op = attnF + (size_t)mb * PANEL + ((size_t)kc * 128 + mm) * 8 + (e0 & 7);
  *(uint32_t*)op = (uint32_t)f2h(ax) | ((uint32_t)f2h(ay) << 16);
}

// ---------------- launcher ----------------
extern "C" void kernel_launch(void* const* d_in, const int* in_sizes, int n_in,
                              void* d_out, int out_size, void* d_ws, size_t ws_size,
                              hipStream_t stream) {
  (void)in_sizes; (void)n_in; (void)out_size; (void)ws_size;
  const float* x  = (const float*)d_in[0];
  const float* Wq = (const float*)d_in[1];
  const float* bq = (const float*)d_in[2];
  const float* Wk = (const float*)d_in[3];
  const float* bk = (const float*)d_in[4];
  const float* Wv = (const float*)d_in[5];
  const float* bv = (const float*)d_in[6];
  const float* Wo = (const float*)d_in[7];
  const float* bo = (const float*)d_in[8];
  const int* dil  = (const int*)d_in[9];
  float* out = (float*)d_out;

  char* ws = (char*)d_ws;
  u16* xhf = (u16*)ws;  ws += (size_t)Mm * Kk * 2;             // 8 MB  frag-major [mb][kc][mm][8]
  u16* wT  = (u16*)ws;  ws += (size_t)24 * Ee * Kk * 2;        // 6 MB  frag-major [z][kc][n][8]
  u16* woT = (u16*)ws;  ws += (size_t)Kk * Dd * 2;             // 2 MB  frag-major [nb][kc][nn][8]
  u16* q = (u16*)ws; ws += (size_t)Bb * Hh * Ss * Ee * 2;      // 8 MB each, f16 [bh][s][e]
  u16* k = (u16*)ws; ws += (size_t)Bb * Hh * Ss * Ee * 2;
  u16* v = (u16*)ws; ws += (size_t)Bb * Hh * Ss * Ee * 2;
  // attnF (8 MB f16, frag-major) aliases xhf — dead after gemm_qkv (stream-ordered)
  u16* attnF = xhf;

  prep<<<8192, 256, 0, stream>>>(x, Wq, Wk, Wv, Wo, xhf, wT, woT);
  gemm_qkv<<<768, 256, 0, stream>>>(xhf, wT, bq, bk, bv, q, k, v);
  attn_kernel<<<(Bb * Hh * Ss) / 4, 256, 0, stream>>>(q, k, v, bk, bv, dil, attnF);
  gemm_out<<<512, 256, 0, stream>>>(attnF, woT, bo, out);
}

// Round 12
// 177.548 us; speedup vs baseline: 1.0129x; 1.0129x over previous
//
#include <hip/hip_runtime.h>
#include <stdint.h>

#define Bb 2
#define Ss 2048
#define Dd 1024
#define Hh 8
#define Ee 128
#define KWW 16
#define Mm (Bb*Ss)   // 4096
#define Kk 1024      // K for both GEMMs
#define PANEL 131072 // 128 cols x 1024 k, frag-major [kc 128][r 128][8]

typedef unsigned short u16;
typedef __attribute__((ext_vector_type(8))) _Float16 f16x8;  // 8 fp16 (4 VGPRs)
typedef __attribute__((ext_vector_type(4))) float f32x4;

__device__ __forceinline__ u16 f2h(float f) {
  union { _Float16 h; u16 u; } v; v.h = (_Float16)f; return v.u;
}
__device__ __forceinline__ float h2f(u16 u) {
  union { u16 u; _Float16 h; } v; v.u = u; return (float)v.h;
}
__device__ __forceinline__ float h2f_lo(uint32_t w) { return h2f((u16)(w & 0xFFFF)); }
__device__ __forceinline__ float h2f_hi(uint32_t w) { return h2f((u16)(w >> 16)); }

// async global->LDS, 16B per lane. LDS dst wave-uniform base; HW scatters lane*16B.
__device__ __forceinline__ void gll16(const void* g, void* l) {
  __builtin_amdgcn_global_load_lds((const __attribute__((address_space(1))) void*)g,
                                   (__attribute__((address_space(3))) void*)l, 16, 0, 0);
}

// ---------------- fused prep kernel (R8) ----------------
// xh row-major [m][k] f16 (A operand, staged via gll16).
// Weights FRAGMENT-MAJOR [kc][n][8] (B operand, per-lane b128 direct loads).
__global__ __launch_bounds__(256) void prep(
    const float* __restrict__ x, const float* __restrict__ Wq,
    const float* __restrict__ Wk, const float* __restrict__ Wv,
    const float* __restrict__ Wo,
    u16* __restrict__ xh, u16* __restrict__ wT, u16* __restrict__ woT) {
  const int bid = blockIdx.x;
  const int tid = threadIdx.x;
  if (bid < 4096) {
    int i = (bid * 256 + tid) * 4;
    float4 f = *(const float4*)(x + i);
    uint64_t pk = (uint64_t)f2h(f.x) | ((uint64_t)f2h(f.y) << 16) |
                  ((uint64_t)f2h(f.z) << 32) | ((uint64_t)f2h(f.w) << 48);
    *(uint64_t*)(xh + i) = pk;
    return;
  }
  __shared__ float tile[32][33];  // +1 pad: bank-conflict-free
  const int tx = tid & 31, ty = tid >> 5;  // (32,8) shape
  if (bid < 4096 + 3072) {
    const int idx = bid - 4096;
    const int z = idx >> 7, rem = idx & 127;
    const int h = z & 7;
    const float* W = (z < 8) ? Wq : (z < 16) ? Wk : Wv;
    const float* ib = W + (size_t)h * Dd * Ee;
    u16* ob = wT + (size_t)z * PANEL;
    const int r0 = (rem & 31) * 32, c0 = (rem >> 5) * 32;  // r over D(=k), c over E(=n)
    #pragma unroll
    for (int kq = 0; kq < 4; kq++)
      tile[ty + 8*kq][tx] = ib[(size_t)(r0 + ty + 8*kq) * Ee + (c0 + tx)];
    __syncthreads();
    const int k = r0 + tx;
    #pragma unroll
    for (int kq = 0; kq < 4; kq++) {
      const int n = c0 + ty + 8*kq;
      ob[(((size_t)(k >> 3) * 128 + n) << 3) + (k & 7)] = f2h(tile[tx][ty + 8*kq]);
    }
  } else {
    const int idx = bid - (4096 + 3072);
    const int r0 = (idx & 31) * 32, c0 = (idx >> 5) * 32;  // r over h*E(=k), c over D(=n)
    #pragma unroll
    for (int kq = 0; kq < 4; kq++)
      tile[ty + 8*kq][tx] = Wo[(size_t)(r0 + ty + 8*kq) * Dd + (c0 + tx)];
    __syncthreads();
    const int k = r0 + tx;
    #pragma unroll
    for (int kq = 0; kq < 4; kq++) {
      const int n = c0 + ty + 8*kq;
      woT[(size_t)(n >> 7) * PANEL +
          (((size_t)(k >> 3) * 128 + (n & 127)) << 3) + (k & 7)] = f2h(tile[tx][ty + 8*kq]);
    }
  }
}

// ---------------- R8 GEMM core (gemm_out): LDS-dbuf A + direct B, BK=64 ----------------
template<int MT>   // 64
__device__ __forceinline__ void gemm_core(
    const u16* __restrict__ A, const u16* __restrict__ Btf,
    u16* As, f32x4 (&acc)[MT / 32][4]) {
  constexpr int MI = MT / 32;
  const int tid = threadIdx.x;
  const int wave = tid >> 6;
  const int lane = tid & 63;
  const size_t lnoff = (size_t)(lane >> 3) * Kk + (size_t)(((lane & 7) ^ (lane >> 3)) * 8);

  const int wm = (wave >> 1) * (MT / 2);
  const int wn = (wave & 1) * 64;
  const int fr = lane & 15;
  const int q  = lane >> 4;
  const int sw = fr & 7;

  const u16* bptr = Btf + ((size_t)q * 128 + wn + fr) * 8;
  f16x8 bcur[8], bnxt[8];
  #pragma unroll
  for (int ks = 0; ks < 2; ks++)
    #pragma unroll
    for (int j = 0; j < 4; j++)
      bcur[ks * 4 + j] = *(const f16x8*)(bptr + (ks * 4) * 1024 + j * 128);

  #pragma unroll
  for (int i = 0; i < MI; i++)
    #pragma unroll
    for (int j = 0; j < 4; j++)
      #pragma unroll
      for (int r = 0; r < 4; r++) acc[i][j][r] = 0.0f;

  #pragma unroll
  for (int c = 0; c < MI; c++)
    gll16(A + lnoff + (size_t)((c * 4 + wave) * 8) * Kk, As + (c * 4 + wave) * 512);
  __syncthreads();

  for (int w = 0; w < Kk / 64; w++) {
    const int kt = w * 64;
    u16* cur = As + (w & 1) * (MT * 64);
    u16* nxt = As + ((w + 1) & 1) * (MT * 64);
    if (w + 1 < Kk / 64) {
      #pragma unroll
      for (int c = 0; c < MI; c++)
        gll16(A + lnoff + (size_t)((c * 4 + wave) * 8) * Kk + kt + 64, nxt + (c * 4 + wave) * 512);
    }
    const int ktn = (kt + 64) & (Kk - 1);
    #pragma unroll
    for (int ks = 0; ks < 2; ks++)
      #pragma unroll
      for (int j = 0; j < 4; j++)
        bnxt[ks * 4 + j] = *(const f16x8*)(bptr + ((ktn >> 3) + ks * 4) * 1024 + j * 128);
    #pragma unroll
    for (int ks = 0; ks < 2; ks++) {
      const int col = ((ks << 2) | q) ^ sw;
      f16x8 ah[MI];
      #pragma unroll
      for (int i = 0; i < MI; i++)
        ah[i] = *(const f16x8*)(cur + (wm + i * 16 + fr) * 64 + col * 8);
      #pragma unroll
      for (int i = 0; i < MI; i++)
        #pragma unroll
        for (int j = 0; j < 4; j++)
          acc[i][j] = __builtin_amdgcn_mfma_f32_16x16x32_f16(ah[i], bcur[ks * 4 + j], acc[i][j], 0, 0, 0);
    }
    __syncthreads();
    #pragma unroll
    for (int t = 0; t < 8; t++) bcur[t] = bnxt[t];
  }
}

// C/D layout (measured m89/m91): col = lane&15, row = (lane>>4)*4 + reg

// ---------------- NEW: big-tile QKV GEMM — 256x128/block, 64x128/wave ----------------
// 64 MFMAs per window per wave (1240 cyc/SIMD-wave of compute vs ~12 loads):
// the wave's own MFMA stream covers load latency (R11 ledger: all 16-MFMA/window
// structures stall ~500 cyc/window regardless of staging scheme).
// A: LDS dbuf 2x32KB, XOR-swizzle (conflicts=0, R5). B: frag-major direct, ks-dbuf.
// 384 blocks, launch_bounds(256,2): all blocks resident (<=2/CU), acc 128 VGPRs.
__global__ __launch_bounds__(256, 2) void gemm_qkv(
    const u16* __restrict__ xh, const u16* __restrict__ wT,
    const float* __restrict__ bq, const float* __restrict__ bk, const float* __restrict__ bv,
    u16* __restrict__ q, u16* __restrict__ k, u16* __restrict__ v) {
  __shared__ u16 As[256 * 64 * 2];   // 64 KB
  const int bid = blockIdx.x;        // 384 = 16 mb2 x 24 z
  const int mb2 = bid & 15, z = bid >> 4;
  const int m0 = mb2 * 256;
  const int proj = z >> 3, h = z & 7;

  const int tid = threadIdx.x, wave = tid >> 6, lane = tid & 63;
  const size_t lnoff = (size_t)(lane >> 3) * Kk + (size_t)(((lane & 7) ^ (lane >> 3)) * 8);
  const u16* Arow = xh + (size_t)m0 * Kk;
  const int fr = lane & 15, qd = lane >> 4;
  const int sw = fr & 7;
  const int wmrow = wave * 64;       // wave owns rows [wave*64, wave*64+64)

  const u16* bptr = wT + (size_t)z * PANEL + ((size_t)qd * 128 + fr) * 8;

  f32x4 acc[4][8];
  #pragma unroll
  for (int i = 0; i < 4; i++)
    #pragma unroll
    for (int j = 0; j < 8; j++)
      #pragma unroll
      for (int r = 0; r < 4; r++) acc[i][j][r] = 0.0f;

  f16x8 bA[8], bB[8];
  // stage A window w into buf: 32 groups of 8 rows; wave handles g = c*4+wave
  auto stageA = [&](int w, u16* buf) {
    const size_t kt = (size_t)w * 64;
    #pragma unroll
    for (int c = 0; c < 8; c++) {
      const int g = c * 4 + wave;
      gll16(Arow + lnoff + (size_t)(g * 8) * Kk + kt, buf + g * 512);
    }
  };
  auto loadB = [&](int w, int ks, f16x8 (&bb)[8]) {
    const size_t o = (size_t)(w & 15) * 8192 + (size_t)ks * 4096;
    #pragma unroll
    for (int j = 0; j < 8; j++) bb[j] = *(const f16x8*)(bptr + o + (size_t)j * 128);
  };

  stageA(0, As);
  loadB(0, 0, bA);
  __syncthreads();

  for (int w = 0; w < 16; w++) {
    u16* cur = As + (w & 1) * 16384;
    u16* nxt = As + ((w + 1) & 1) * 16384;
    if (w + 1 < 16) stageA(w + 1, nxt);
    loadB(w, 1, bB);
    {   // ks = 0 from bA
      const int col = qd ^ sw;
      f16x8 ah[4];
      #pragma unroll
      for (int i = 0; i < 4; i++)
        ah[i] = *(const f16x8*)(cur + (wmrow + i * 16 + fr) * 64 + col * 8);
      #pragma unroll
      for (int i = 0; i < 4; i++)
        #pragma unroll
        for (int j = 0; j < 8; j++)
          acc[i][j] = __builtin_amdgcn_mfma_f32_16x16x32_f16(ah[i], bA[j], acc[i][j], 0, 0, 0);
    }
    loadB(w + 1, 0, bA);   // prefetch next window's ks=0 (wrap-safe)
    {   // ks = 1 from bB
      const int col = (4 | qd) ^ sw;
      f16x8 ah[4];
      #pragma unroll
      for (int i = 0; i < 4; i++)
        ah[i] = *(const f16x8*)(cur + (wmrow + i * 16 + fr) * 64 + col * 8);
      #pragma unroll
      for (int i = 0; i < 4; i++)
        #pragma unroll
        for (int j = 0; j < 8; j++)
          acc[i][j] = __builtin_amdgcn_mfma_f32_16x16x32_f16(ah[i], bB[j], acc[i][j], 0, 0, 0);
    }
    __syncthreads();   // single barrier: cur reads done + nxt staging drained
  }

  u16* dst = proj == 0 ? q : (proj == 1 ? k : v);
  const float* bias = proj == 0 ? bq : (proj == 1 ? bk : bv);
  const int cn = lane & 15, rq4 = (lane >> 4) * 4;
  #pragma unroll
  for (int j = 0; j < 8; j++) {
    const int e = j * 16 + cn;
    const float bbias = bias[h * Ee + e];
    #pragma unroll
    for (int i = 0; i < 4; i++) {
      #pragma unroll
      for (int r = 0; r < 4; r++) {
        const int m = m0 + wmrow + i * 16 + rq4 + r;   // m = b*S + s
        const int b = m >> 11, s = m & (Ss - 1);
        dst[(((size_t)(b * Hh + h)) * Ss + s) * Ee + e] = f2h(acc[i][j][r] + bbias);
      }
    }
  }
}

__global__ __launch_bounds__(256) void gemm_out(
    const u16* __restrict__ attn, const u16* __restrict__ woT,
    const float* __restrict__ bo, float* __restrict__ out) {
  __shared__ u16 As[64 * 64 * 2];
  const int m0 = blockIdx.x * 64;
  const int n0 = blockIdx.y * 128;
  f32x4 acc[2][4];
  gemm_core<64>(attn + (size_t)m0 * Kk, woT + (size_t)blockIdx.y * PANEL, As, acc);
  const int wave = threadIdx.x >> 6, lane = threadIdx.x & 63;
  const int wm = (wave >> 1) * 32, wn = (wave & 1) * 64;
  const int cn = lane & 15, rq4 = (lane >> 4) * 4;
  #pragma unroll
  for (int j = 0; j < 4; j++) {
    const int n = n0 + wn + j * 16 + cn;
    const float bb = bo[n];
    #pragma unroll
    for (int i = 0; i < 2; i++) {
      #pragma unroll
      for (int r = 0; r < 4; r++) {
        const int m = m0 + wm + i * 16 + rq4 + r;
        out[(size_t)m * Dd + n] = acc[i][j][r] + bb;
      }
    }
  }
}

// ---------------- attention (R8): one wave per (b,h,s), row-major output ----------------
__global__ __launch_bounds__(256) void attn_kernel(
    const u16* __restrict__ q, const u16* __restrict__ k, const u16* __restrict__ v,
    const float* __restrict__ bk, const float* __restrict__ bv,
    const int* __restrict__ dil, u16* __restrict__ attn) {
  const int nblk = (Bb * Hh * Ss) / 4;           // 8192
  const int blk = (blockIdx.x & 7) * (nblk / 8) + (blockIdx.x >> 3);
  const int wid = blk * 4 + (threadIdx.x >> 6);
  const int lane = threadIdx.x & 63;
  const int s = wid & (Ss - 1);
  const int bh = wid >> 11;
  const int h = bh & 7, b = bh >> 3;
  const int d = dil[h];
  const size_t base = (size_t)bh * Ss * Ee;
  const u16* kp = k + base;
  const u16* vp = v + base;
  const uint32_t qw = *(const uint32_t*)(q + base + (size_t)s * Ee + 2 * lane);
  const float qx = h2f_lo(qw), qy = h2f_hi(qw);
  const float2 bk2 = ((const float2*)(bk + h * Ee))[lane];
  const float2 bv2 = ((const float2*)(bv + h * Ee))[lane];
  const int off = (d * (KWW - 1)) >> 1;
  const int J = (lane >> 2) & 15;

  float logit[KWW];
  #pragma unroll
  for (int j = 0; j < KWW; j++) {
    const int pos = s + d * j - off;
    if (pos >= 0 && pos < Ss) {
      uint32_t kw = *(const uint32_t*)(kp + (size_t)pos * Ee + 2 * lane);
      logit[j] = qx * h2f_lo(kw) + qy * h2f_hi(kw);
    } else {
      logit[j] = qx * bk2.x + qy * bk2.y;  // padded key = bias (NOT masked)
    }
  }
  float vvx[KWW], vvy[KWW];
  #pragma unroll
  for (int t = 0; t < KWW; t++) {
    const int j = J ^ t;
    const int pos = s + d * j - off;
    const int posc = min(max(pos, 0), Ss - 1);
    uint32_t vw = *(const uint32_t*)(vp + (size_t)posc * Ee + 2 * lane);
    const bool ok = (pos >= 0) && (pos < Ss);
    vvx[t] = ok ? h2f_lo(vw) : bv2.x;
    vvy[t] = ok ? h2f_hi(vw) : bv2.y;
  }

  {
    const bool hi = (lane & 32) != 0;
    #pragma unroll
    for (int j = 0; j < 8; j++) {
      float send = hi ? logit[j] : logit[j + 8];
      float recv = __shfl_xor(send, 32, 64);
      logit[j] = (hi ? logit[j + 8] : logit[j]) + recv;
    }
  }
  {
    const bool hi = (lane & 16) != 0;
    #pragma unroll
    for (int j = 0; j < 4; j++) {
      float send = hi ? logit[j] : logit[j + 4];
      float recv = __shfl_xor(send, 16, 64);
      logit[j] = (hi ? logit[j + 4] : logit[j]) + recv;
    }
  }
  {
    const bool hi = (lane & 8) != 0;
    #pragma unroll
    for (int j = 0; j < 2; j++) {
      float send = hi ? logit[j] : logit[j + 2];
      float recv = __shfl_xor(send, 8, 64);
      logit[j] = (hi ? logit[j + 2] : logit[j]) + recv;
    }
  }
  float own;
  {
    const bool hi = (lane & 4) != 0;
    float send = hi ? logit[0] : logit[1];
    float recv = __shfl_xor(send, 4, 64);
    own = (hi ? logit[1] : logit[0]) + recv;
  }
  own += __shfl_xor(own, 2, 64);
  own += __shfl_xor(own, 1, 64);

  float mx = own;
  mx = fmaxf(mx, __shfl_xor(mx, 4, 64));
  mx = fmaxf(mx, __shfl_xor(mx, 8, 64));
  mx = fmaxf(mx, __shfl_xor(mx, 16, 64));
  mx = fmaxf(mx, __shfl_xor(mx, 32, 64));
  float w = __expf(own - mx);
  float sum = w;
  sum += __shfl_xor(sum, 4, 64);
  sum += __shfl_xor(sum, 8, 64);
  sum += __shfl_xor(sum, 16, 64);
  sum += __shfl_xor(sum, 32, 64);
  w *= 1.0f / (sum * 11.313708498984760f);  // /Z /sqrt(E), post-softmax quirk

  float g[KWW];
  g[0] = w;
  g[1] = __shfl_xor(g[0], 4, 64);
  #pragma unroll
  for (int t = 0; t < 2; t++) g[2 + t] = __shfl_xor(g[t], 8, 64);
  #pragma unroll
  for (int t = 0; t < 4; t++) g[4 + t] = __shfl_xor(g[t], 16, 64);
  #pragma unroll
  for (int t = 0; t < 8; t++) g[8 + t] = __shfl_xor(g[t], 32, 64);

  float ax = 0.f, ay = 0.f;
  #pragma unroll
  for (int t = 0; t < KWW; t++) { ax += g[t] * vvx[t]; ay += g[t] * vvy[t]; }

  u16* op = attn + ((size_t)(b * Ss + s)) * (Hh * Ee) + h * Ee + 2 * lane;
  *(uint32_t*)op = (uint32_t)f2h(ax) | ((uint32_t)f2h(ay) << 16);
}

// ---------------- launcher ----------------
extern "C" void kernel_launch(void* const* d_in, const int* in_sizes, int n_in,
                              void* d_out, int out_size, void* d_ws, size_t ws_size,
                              hipStream_t stream) {
  (void)in_sizes; (void)n_in; (void)out_size; (void)ws_size;
  const float* x  = (const float*)d_in[0];
  const float* Wq = (const float*)d_in[1];
  const float* bq = (const float*)d_in[2];
  const float* Wk = (const float*)d_in[3];
  const float* bk = (const float*)d_in[4];
  const float* Wv = (const float*)d_in[5];
  const float* bv = (const float*)d_in[6];
  const float* Wo = (const float*)d_in[7];
  const float* bo = (const float*)d_in[8];
  const int* dil  = (const int*)d_in[9];
  float* out = (float*)d_out;

  char* ws = (char*)d_ws;
  u16* xh  = (u16*)ws;  ws += (size_t)Mm * Kk * 2;             // 8 MB  row-major [m][k]
  u16* wT  = (u16*)ws;  ws += (size_t)24 * Ee * Kk * 2;        // 6 MB  frag-major [z][kc][n][8]
  u16* woT = (u16*)ws;  ws += (size_t)Kk * Dd * 2;             // 2 MB  frag-major [nb][kc][nn][8]
  u16* q = (u16*)ws; ws += (size_t)Bb * Hh * Ss * Ee * 2;      // 8 MB each, f16 [bh][s][e]
  u16* k = (u16*)ws; ws += (size_t)Bb * Hh * Ss * Ee * 2;
  u16* v = (u16*)ws; ws += (size_t)Bb * Hh * Ss * Ee * 2;
  u16* attn = xh;   // aliases xh — dead after gemm_qkv (stream-ordered)

  prep<<<8192, 256, 0, stream>>>(x, Wq, Wk, Wv, Wo, xh, wT, woT);
  gemm_qkv<<<384, 256, 0, stream>>>(xh, wT, bq, bk, bv, q, k, v);
  attn_kernel<<<(Bb * Hh * Ss) / 4, 256, 0, stream>>>(q, k, v, bk, bv, dil, attn);
  gemm_out<<<dim3(Mm / 64, Dd / 128), 256, 0, stream>>>(attn, woT, bo, out);
}

// Round 13
// 175.150 us; speedup vs baseline: 1.0268x; 1.0137x over previous
//
#include <hip/hip_runtime.h>
#include <stdint.h>

#define Bb 2
#define Ss 2048
#define Dd 1024
#define Hh 8
#define Ee 128
#define KWW 16
#define Mm (Bb*Ss)   // 4096
#define Kk 1024      // K for both GEMMs
#define PANEL 131072 // 128 cols x 1024 k, frag-major [kc 128][r 128][8]

typedef unsigned short u16;
typedef __attribute__((ext_vector_type(8))) _Float16 f16x8;  // 8 fp16 (4 VGPRs)
typedef __attribute__((ext_vector_type(4))) float f32x4;

__device__ __forceinline__ u16 f2h(float f) {
  union { _Float16 h; u16 u; } v; v.h = (_Float16)f; return v.u;
}
__device__ __forceinline__ float h2f(u16 u) {
  union { u16 u; _Float16 h; } v; v.u = u; return (float)v.h;
}
__device__ __forceinline__ float h2f_lo(uint32_t w) { return h2f((u16)(w & 0xFFFF)); }
__device__ __forceinline__ float h2f_hi(uint32_t w) { return h2f((u16)(w >> 16)); }

// async global->LDS, 16B per lane. LDS dst wave-uniform base; HW scatters lane*16B.
__device__ __forceinline__ void gll16(const void* g, void* l) {
  __builtin_amdgcn_global_load_lds((const __attribute__((address_space(1))) void*)g,
                                   (__attribute__((address_space(3))) void*)l, 16, 0, 0);
}

// ---------------- fused prep kernel (R8) ----------------
// xh row-major [m][k] f16 (A operand, staged via gll16).
// Weights FRAGMENT-MAJOR [kc][n][8] (B operand, per-lane b128 direct loads).
__global__ __launch_bounds__(256) void prep(
    const float* __restrict__ x, const float* __restrict__ Wq,
    const float* __restrict__ Wk, const float* __restrict__ Wv,
    const float* __restrict__ Wo,
    u16* __restrict__ xh, u16* __restrict__ wT, u16* __restrict__ woT) {
  const int bid = blockIdx.x;
  const int tid = threadIdx.x;
  if (bid < 4096) {
    int i = (bid * 256 + tid) * 4;
    float4 f = *(const float4*)(x + i);
    uint64_t pk = (uint64_t)f2h(f.x) | ((uint64_t)f2h(f.y) << 16) |
                  ((uint64_t)f2h(f.z) << 32) | ((uint64_t)f2h(f.w) << 48);
    *(uint64_t*)(xh + i) = pk;
    return;
  }
  __shared__ float tile[32][33];  // +1 pad: bank-conflict-free
  const int tx = tid & 31, ty = tid >> 5;  // (32,8) shape
  if (bid < 4096 + 3072) {
    const int idx = bid - 4096;
    const int z = idx >> 7, rem = idx & 127;
    const int h = z & 7;
    const float* W = (z < 8) ? Wq : (z < 16) ? Wk : Wv;
    const float* ib = W + (size_t)h * Dd * Ee;
    u16* ob = wT + (size_t)z * PANEL;
    const int r0 = (rem & 31) * 32, c0 = (rem >> 5) * 32;  // r over D(=k), c over E(=n)
    #pragma unroll
    for (int kq = 0; kq < 4; kq++)
      tile[ty + 8*kq][tx] = ib[(size_t)(r0 + ty + 8*kq) * Ee + (c0 + tx)];
    __syncthreads();
    const int k = r0 + tx;
    #pragma unroll
    for (int kq = 0; kq < 4; kq++) {
      const int n = c0 + ty + 8*kq;
      ob[(((size_t)(k >> 3) * 128 + n) << 3) + (k & 7)] = f2h(tile[tx][ty + 8*kq]);
    }
  } else {
    const int idx = bid - (4096 + 3072);
    const int r0 = (idx & 31) * 32, c0 = (idx >> 5) * 32;  // r over h*E(=k), c over D(=n)
    #pragma unroll
    for (int kq = 0; kq < 4; kq++)
      tile[ty + 8*kq][tx] = Wo[(size_t)(r0 + ty + 8*kq) * Dd + (c0 + tx)];
    __syncthreads();
    const int k = r0 + tx;
    #pragma unroll
    for (int kq = 0; kq < 4; kq++) {
      const int n = c0 + ty + 8*kq;
      woT[(size_t)(n >> 7) * PANEL +
          (((size_t)(k >> 3) * 128 + (n & 127)) << 3) + (k & 7)] = f2h(tile[tx][ty + 8*kq]);
    }
  }
}

// ---------------- R8 GEMM core (gemm_out): LDS-dbuf A + direct B, BK=64 ----------------
template<int MT>   // 64
__device__ __forceinline__ void gemm_core(
    const u16* __restrict__ A, const u16* __restrict__ Btf,
    u16* As, f32x4 (&acc)[MT / 32][4]) {
  constexpr int MI = MT / 32;
  const int tid = threadIdx.x;
  const int wave = tid >> 6;
  const int lane = tid & 63;
  const size_t lnoff = (size_t)(lane >> 3) * Kk + (size_t)(((lane & 7) ^ (lane >> 3)) * 8);

  const int wm = (wave >> 1) * (MT / 2);
  const int wn = (wave & 1) * 64;
  const int fr = lane & 15;
  const int q  = lane >> 4;
  const int sw = fr & 7;

  const u16* bptr = Btf + ((size_t)q * 128 + wn + fr) * 8;
  f16x8 bcur[8], bnxt[8];
  #pragma unroll
  for (int ks = 0; ks < 2; ks++)
    #pragma unroll
    for (int j = 0; j < 4; j++)
      bcur[ks * 4 + j] = *(const f16x8*)(bptr + (ks * 4) * 1024 + j * 128);

  #pragma unroll
  for (int i = 0; i < MI; i++)
    #pragma unroll
    for (int j = 0; j < 4; j++)
      #pragma unroll
      for (int r = 0; r < 4; r++) acc[i][j][r] = 0.0f;

  #pragma unroll
  for (int c = 0; c < MI; c++)
    gll16(A + lnoff + (size_t)((c * 4 + wave) * 8) * Kk, As + (c * 4 + wave) * 512);
  __syncthreads();

  for (int w = 0; w < Kk / 64; w++) {
    const int kt = w * 64;
    u16* cur = As + (w & 1) * (MT * 64);
    u16* nxt = As + ((w + 1) & 1) * (MT * 64);
    const int ktn = (kt + 64) & (Kk - 1);
    #pragma unroll
    for (int ks = 0; ks < 2; ks++)
      #pragma unroll
      for (int j = 0; j < 4; j++)
        bnxt[ks * 4 + j] = *(const f16x8*)(bptr + ((ktn >> 3) + ks * 4) * 1024 + j * 128);
    if (w + 1 < Kk / 64) {
      #pragma unroll
      for (int c = 0; c < MI; c++)
        gll16(A + lnoff + (size_t)((c * 4 + wave) * 8) * Kk + kt + 64, nxt + (c * 4 + wave) * 512);
    }
    #pragma unroll
    for (int ks = 0; ks < 2; ks++) {
      const int col = ((ks << 2) | q) ^ sw;
      f16x8 ah[MI];
      #pragma unroll
      for (int i = 0; i < MI; i++)
        ah[i] = *(const f16x8*)(cur + (wm + i * 16 + fr) * 64 + col * 8);
      #pragma unroll
      for (int i = 0; i < MI; i++)
        #pragma unroll
        for (int j = 0; j < 4; j++)
          acc[i][j] = __builtin_amdgcn_mfma_f32_16x16x32_f16(ah[i], bcur[ks * 4 + j], acc[i][j], 0, 0, 0);
    }
    __syncthreads();
    #pragma unroll
    for (int t = 0; t < 8; t++) bcur[t] = bnxt[t];
  }
}

// C/D layout (measured m89/m91): col = lane&15, row = (lane>>4)*4 + reg

// ---------------- big-tile QKV GEMM — 256x128/block, wave grid 2x2 ----------------
// R13: wave = 128m x 64n (MI=8 x NJ=4, acc 128 VGPR) — B redundancy 4x->2x,
// per-block-window VMEM 96->64 KB (R12 was cache-port co-limited: VALU 11%,
// HBM 21%, MFMA 22%). loadB(w,ks1) issued BEFORE stageA(w+1) so the ks1
// s_waitcnt drains only L2-fast B loads, not the gll16 queue (in-order vmcnt).
// A: LDS dbuf 2x32KB, XOR-swizzle (conflicts=0, R5). 384 blocks, 2 blocks/CU.
__global__ __launch_bounds__(256, 2) void gemm_qkv(
    const u16* __restrict__ xh, const u16* __restrict__ wT,
    const float* __restrict__ bq, const float* __restrict__ bk, const float* __restrict__ bv,
    u16* __restrict__ q, u16* __restrict__ k, u16* __restrict__ v) {
  __shared__ u16 As[256 * 64 * 2];   // 64 KB
  const int bid = blockIdx.x;        // 384 = 16 mb2 x 24 z
  const int mb2 = bid & 15, z = bid >> 4;
  const int m0 = mb2 * 256;
  const int proj = z >> 3, h = z & 7;

  const int tid = threadIdx.x, wave = tid >> 6, lane = tid & 63;
  const size_t lnoff = (size_t)(lane >> 3) * Kk + (size_t)(((lane & 7) ^ (lane >> 3)) * 8);
  const u16* Arow = xh + (size_t)m0 * Kk;
  const int fr = lane & 15, qd = lane >> 4;
  const int sw = fr & 7;
  const int wm = (wave >> 1) * 128;  // m-half: rows [wm, wm+128)
  const int wn = (wave & 1) * 64;    // n-half: cols [wn, wn+64)

  const u16* bptr = wT + (size_t)z * PANEL + ((size_t)qd * 128 + wn + fr) * 8;

  f32x4 acc[8][4];
  #pragma unroll
  for (int i = 0; i < 8; i++)
    #pragma unroll
    for (int j = 0; j < 4; j++)
      #pragma unroll
      for (int r = 0; r < 4; r++) acc[i][j][r] = 0.0f;

  f16x8 bA[4], bB[4];
  // stage A window w into buf: 32 groups of 8 rows; wave handles g = c*4+wave
  auto stageA = [&](int w, u16* buf) {
    const size_t kt = (size_t)w * 64;
    #pragma unroll
    for (int c = 0; c < 8; c++) {
      const int g = c * 4 + wave;
      gll16(Arow + lnoff + (size_t)(g * 8) * Kk + kt, buf + g * 512);
    }
  };
  auto loadB = [&](int w, int ks, f16x8 (&bb)[4]) {
    const size_t o = (size_t)(w & 15) * 8192 + (size_t)ks * 4096;
    #pragma unroll
    for (int j = 0; j < 4; j++) bb[j] = *(const f16x8*)(bptr + o + (size_t)j * 128);
  };
  auto compKS = [&](const u16* cur, int ks, f16x8 (&bb)[4]) {
    const int col = ((ks << 2) | qd) ^ sw;
    f16x8 ah[8];
    #pragma unroll
    for (int i = 0; i < 8; i++)
      ah[i] = *(const f16x8*)(cur + (wm + i * 16 + fr) * 64 + col * 8);
    #pragma unroll
    for (int i = 0; i < 8; i++)
      #pragma unroll
      for (int j = 0; j < 4; j++)
        acc[i][j] = __builtin_amdgcn_mfma_f32_16x16x32_f16(ah[i], bb[j], acc[i][j], 0, 0, 0);
  };

  stageA(0, As);
  loadB(0, 0, bA);
  __syncthreads();

  for (int w = 0; w < 16; w++) {
    u16* cur = As + (w & 1) * 16384;
    u16* nxt = As + ((w + 1) & 1) * 16384;
    loadB(w, 1, bB);               // BEFORE stageA: ks1 wait drains only these
    if (w + 1 < 16) stageA(w + 1, nxt);
    compKS(cur, 0, bA);            // ks = 0
    loadB(w + 1, 0, bA);           // next window ks=0 (bA dead; barrier covers it)
    compKS(cur, 1, bB);            // ks = 1
    __syncthreads();               // cur reads done + nxt staging drained
  }

  u16* dst = proj == 0 ? q : (proj == 1 ? k : v);
  const float* bias = proj == 0 ? bq : (proj == 1 ? bk : bv);
  const int cn = lane & 15, rq4 = (lane >> 4) * 4;
  #pragma unroll
  for (int j = 0; j < 4; j++) {
    const int e = wn + j * 16 + cn;
    const float bbias = bias[h * Ee + e];
    #pragma unroll
    for (int i = 0; i < 8; i++) {
      #pragma unroll
      for (int r = 0; r < 4; r++) {
        const int m = m0 + wm + i * 16 + rq4 + r;   // m = b*S + s
        const int b = m >> 11, s = m & (Ss - 1);
        dst[(((size_t)(b * Hh + h)) * Ss + s) * Ee + e] = f2h(acc[i][j][r] + bbias);
      }
    }
  }
}

__global__ __launch_bounds__(256) void gemm_out(
    const u16* __restrict__ attn, const u16* __restrict__ woT,
    const float* __restrict__ bo, float* __restrict__ out) {
  __shared__ u16 As[64 * 64 * 2];
  const int m0 = blockIdx.x * 64;
  const int n0 = blockIdx.y * 128;
  f32x4 acc[2][4];
  gemm_core<64>(attn + (size_t)m0 * Kk, woT + (size_t)blockIdx.y * PANEL, As, acc);
  const int wave = threadIdx.x >> 6, lane = threadIdx.x & 63;
  const int wm = (wave >> 1) * 32, wn = (wave & 1) * 64;
  const int cn = lane & 15, rq4 = (lane >> 4) * 4;
  #pragma unroll
  for (int j = 0; j < 4; j++) {
    const int n = n0 + wn + j * 16 + cn;
    const float bb = bo[n];
    #pragma unroll
    for (int i = 0; i < 2; i++) {
      #pragma unroll
      for (int r = 0; r < 4; r++) {
        const int m = m0 + wm + i * 16 + rq4 + r;
        out[(size_t)m * Dd + n] = acc[i][j][r] + bb;
      }
    }
  }
}

// ---------------- attention (R8): one wave per (b,h,s), row-major output ----------------
__global__ __launch_bounds__(256) void attn_kernel(
    const u16* __restrict__ q, const u16* __restrict__ k, const u16* __restrict__ v,
    const float* __restrict__ bk, const float* __restrict__ bv,
    const int* __restrict__ dil, u16* __restrict__ attn) {
  const int nblk = (Bb * Hh * Ss) / 4;           // 8192
  const int blk = (blockIdx.x & 7) * (nblk / 8) + (blockIdx.x >> 3);
  const int wid = blk * 4 + (threadIdx.x >> 6);
  const int lane = threadIdx.x & 63;
  const int s = wid & (Ss - 1);
  const int bh = wid >> 11;
  const int h = bh & 7, b = bh >> 3;
  const int d = dil[h];
  const size_t base = (size_t)bh * Ss * Ee;
  const u16* kp = k + base;
  const u16* vp = v + base;
  const uint32_t qw = *(const uint32_t*)(q + base + (size_t)s * Ee + 2 * lane);
  const float qx = h2f_lo(qw), qy = h2f_hi(qw);
  const float2 bk2 = ((const float2*)(bk + h * Ee))[lane];
  const float2 bv2 = ((const float2*)(bv + h * Ee))[lane];
  const int off = (d * (KWW - 1)) >> 1;
  const int J = (lane >> 2) & 15;

  float logit[KWW];
  #pragma unroll
  for (int j = 0; j < KWW; j++) {
    const int pos = s + d * j - off;
    if (pos >= 0 && pos < Ss) {
      uint32_t kw = *(const uint32_t*)(kp + (size_t)pos * Ee + 2 * lane);
      logit[j] = qx * h2f_lo(kw) + qy * h2f_hi(kw);
    } else {
      logit[j] = qx * bk2.x + qy * bk2.y;  // padded key = bias (NOT masked)
    }
  }
  float vvx[KWW], vvy[KWW];
  #pragma unroll
  for (int t = 0; t < KWW; t++) {
    const int j = J ^ t;
    const int pos = s + d * j - off;
    const int posc = min(max(pos, 0), Ss - 1);
    uint32_t vw = *(const uint32_t*)(vp + (size_t)posc * Ee + 2 * lane);
    const bool ok = (pos >= 0) && (pos < Ss);
    vvx[t] = ok ? h2f_lo(vw) : bv2.x;
    vvy[t] = ok ? h2f_hi(vw) : bv2.y;
  }

  {
    const bool hi = (lane & 32) != 0;
    #pragma unroll
    for (int j = 0; j < 8; j++) {
      float send = hi ? logit[j] : logit[j + 8];
      float recv = __shfl_xor(send, 32, 64);
      logit[j] = (hi ? logit[j + 8] : logit[j]) + recv;
    }
  }
  {
    const bool hi = (lane & 16) != 0;
    #pragma unroll
    for (int j = 0; j < 4; j++) {
      float send = hi ? logit[j] : logit[j + 4];
      float recv = __shfl_xor(send, 16, 64);
      logit[j] = (hi ? logit[j + 4] : logit[j]) + recv;
    }
  }
  {
    const bool hi = (lane & 8) != 0;
    #pragma unroll
    for (int j = 0; j < 2; j++) {
      float send = hi ? logit[j] : logit[j + 2];
      float recv = __shfl_xor(send, 8, 64);
      logit[j] = (hi ? logit[j + 2] : logit[j]) + recv;
    }
  }
  float own;
  {
    const bool hi = (lane & 4) != 0;
    float send = hi ? logit[0] : logit[1];
    float recv = __shfl_xor(send, 4, 64);
    own = (hi ? logit[1] : logit[0]) + recv;
  }
  own += __shfl_xor(own, 2, 64);
  own += __shfl_xor(own, 1, 64);

  float mx = own;
  mx = fmaxf(mx, __shfl_xor(mx, 4, 64));
  mx = fmaxf(mx, __shfl_xor(mx, 8, 64));
  mx = fmaxf(mx, __shfl_xor(mx, 16, 64));
  mx = fmaxf(mx, __shfl_xor(mx, 32, 64));
  float w = __expf(own - mx);
  float sum = w;
  sum += __shfl_xor(sum, 4, 64);
  sum += __shfl_xor(sum, 8, 64);
  sum += __shfl_xor(sum, 16, 64);
  sum += __shfl_xor(sum, 32, 64);
  w *= 1.0f / (sum * 11.313708498984760f);  // /Z /sqrt(E), post-softmax quirk

  float g[KWW];
  g[0] = w;
  g[1] = __shfl_xor(g[0], 4, 64);
  #pragma unroll
  for (int t = 0; t < 2; t++) g[2 + t] = __shfl_xor(g[t], 8, 64);
  #pragma unroll
  for (int t = 0; t < 4; t++) g[4 + t] = __shfl_xor(g[t], 16, 64);
  #pragma unroll
  for (int t = 0; t < 8; t++) g[8 + t] = __shfl_xor(g[t], 32, 64);

  float ax = 0.f, ay = 0.f;
  #pragma unroll
  for (int t = 0; t < KWW; t++) { ax += g[t] * vvx[t]; ay += g[t] * vvy[t]; }

  u16* op = attn + ((size_t)(b * Ss + s)) * (Hh * Ee) + h * Ee + 2 * lane;
  *(uint32_t*)op = (uint32_t)f2h(ax) | ((uint32_t)f2h(ay) << 16);
}

// ---------------- launcher ----------------
extern "C" void kernel_launch(void* const* d_in, const int* in_sizes, int n_in,
                              void* d_out, int out_size, void* d_ws, size_t ws_size,
                              hipStream_t stream) {
  (void)in_sizes; (void)n_in; (void)out_size; (void)ws_size;
  const float* x  = (const float*)d_in[0];
  const float* Wq = (const float*)d_in[1];
  const float* bq = (const float*)d_in[2];
  const float* Wk = (const float*)d_in[3];
  const float* bk = (const float*)d_in[4];
  const float* Wv = (const float*)d_in[5];
  const float* bv = (const float*)d_in[6];
  const float* Wo = (const float*)d_in[7];
  const float* bo = (const float*)d_in[8];
  const int* dil  = (const int*)d_in[9];
  float* out = (float*)d_out;

  char* ws = (char*)d_ws;
  u16* xh  = (u16*)ws;  ws += (size_t)Mm * Kk * 2;             // 8 MB  row-major [m][k]
  u16* wT  = (u16*)ws;  ws += (size_t)24 * Ee * Kk * 2;        // 6 MB  frag-major [z][kc][n][8]
  u16* woT = (u16*)ws;  ws += (size_t)Kk * Dd * 2;             // 2 MB  frag-major [nb][kc][nn][8]
  u16* q = (u16*)ws; ws += (size_t)Bb * Hh * Ss * Ee * 2;      // 8 MB each, f16 [bh][s][e]
  u16* k = (u16*)ws; ws += (size_t)Bb * Hh * Ss * Ee * 2;
  u16* v = (u16*)ws; ws += (size_t)Bb * Hh * Ss * Ee * 2;
  u16* attn = xh;   // aliases xh — dead after gemm_qkv (stream-ordered)

  prep<<<8192, 256, 0, stream>>>(x, Wq, Wk, Wv, Wo, xh, wT, woT);
  gemm_qkv<<<384, 256, 0, stream>>>(xh, wT, bq, bk, bv, q, k, v);
  attn_kernel<<<(Bb * Hh * Ss) / 4, 256, 0, stream>>>(q, k, v, bk, bv, dil, attn);
  gemm_out<<<dim3(Mm / 64, Dd / 128), 256, 0, stream>>>(attn, woT, bo, out);
}